// Round 3
// baseline (142.677 us; speedup 1.0000x reference)
//
#include <hip/hip_runtime.h>
#include <math.h>

// Match numpy reference numerics exactly: no FMA contraction anywhere.
// Matching decisions (argmax ties, ov<0.5 threshold) rest on bit-exact floats.
#pragma clang fp contract(off)

#define BB      256
#define PP      3249         // 19*19*9
#define NCLS    21
#define NOBJ    12
#define CELLS   361          // 19*19
#define CH      13           // prior chunks of 256 per batch (13*256 >= 3249)
#define THRESH_ 0.5f

// 4-float vector with 4-byte alignment: conf rows (84 B) are only dword-aligned.
typedef float vf4 __attribute__((ext_vector_type(4), aligned(4)));
// 16-byte-aligned record vector.
typedef float vrec __attribute__((ext_vector_type(4)));

// d_out layout (float32): [0]=loss_l/N, [1]=loss_c/N,
// [2 .. 2+BB*CELLS) = conf_t_featuremap, [2+BB*CELLS .. 2+2*BB*CELLS) = have_centerloss

struct Row { vf4 a, b, c, d, e; float f; };

__device__ __forceinline__ Row load_row(const float* cd) {
    const vf4* q = (const vf4*)cd;
    Row r;
    r.a = q[0]; r.b = q[1]; r.c = q[2]; r.d = q[3]; r.e = q[4];
    r.f = cd[20];
    return r;
}

// lse identical to reference op order: m = max chain k=0..20; s = sum of
// expf(x-m) k=0..20; result logf(s)+m (rounded float -> later ce = lse-conf[c]
// is bit-identical to computing ce inline).
__device__ __forceinline__ float lse21(const Row& r) {
    float m = r.a[0];
    m = fmaxf(m, r.a[1]); m = fmaxf(m, r.a[2]); m = fmaxf(m, r.a[3]);
    m = fmaxf(m, r.b[0]); m = fmaxf(m, r.b[1]); m = fmaxf(m, r.b[2]); m = fmaxf(m, r.b[3]);
    m = fmaxf(m, r.c[0]); m = fmaxf(m, r.c[1]); m = fmaxf(m, r.c[2]); m = fmaxf(m, r.c[3]);
    m = fmaxf(m, r.d[0]); m = fmaxf(m, r.d[1]); m = fmaxf(m, r.d[2]); m = fmaxf(m, r.d[3]);
    m = fmaxf(m, r.e[0]); m = fmaxf(m, r.e[1]); m = fmaxf(m, r.e[2]); m = fmaxf(m, r.e[3]);
    m = fmaxf(m, r.f);
    float s = 0.0f;
    s += expf(r.a[0]-m); s += expf(r.a[1]-m); s += expf(r.a[2]-m); s += expf(r.a[3]-m);
    s += expf(r.b[0]-m); s += expf(r.b[1]-m); s += expf(r.b[2]-m); s += expf(r.b[3]-m);
    s += expf(r.c[0]-m); s += expf(r.c[1]-m); s += expf(r.c[2]-m); s += expf(r.c[3]-m);
    s += expf(r.d[0]-m); s += expf(r.d[1]-m); s += expf(r.d[2]-m); s += expf(r.d[3]-m);
    s += expf(r.e[0]-m); s += expf(r.e[1]-m); s += expf(r.e[2]-m); s += expf(r.e[3]-m);
    s += expf(r.f-m);
    return logf(s) + m;
}

// Ballot-aggregated histogram add: equal-bin lane groups found with NBITS
// ballots; lowest lane of each group does ONE atomicAdd of popcount. Lanes
// not executing (loop tail) are simply absent from the exec-mask ballots.
template <int NBITS>
__device__ __forceinline__ void agg_add(int* hist, bool active, unsigned bin, int lane) {
    unsigned long long mm = __ballot(active);
#pragma unroll
    for (int bit = 0; bit < NBITS; ++bit) {
        unsigned long long bb = __ballot(active && ((bin >> bit) & 1));
        mm &= ((bin >> bit) & 1) ? bb : ~bb;
    }
    if (active && (__ffsll(mm) - 1 == lane))
        atomicAdd(&hist[bin], (int)__popcll(mm));
}

// Wave-0 pick: find the bin where the top-down (descending-bin) cumulative
// count crosses kv. Lane l owns bins [l*per,(l+1)*per) (per>=1); butterfly
// suffix-sum over lanes, then high->low walk within the lane. nbins may be <64.
__device__ __forceinline__ void pick_bin(const int* hist, int nbins, int kv, int lane,
                                         int* s_chosen, int* s_knext, int* s_cnt) {
    const int per = (nbins >= 64) ? (nbins >> 6) : 1;
    const int base = lane * per;
    int ls = 0;
    if (base < nbins)
        for (int k = 0; k < per; ++k) ls += hist[base + k];
    int x = ls;
#pragma unroll
    for (int off = 1; off < 64; off <<= 1) {
        int y = __shfl_down(x, off);
        if (lane + off < 64) x += y;
    }
    int cum = x - ls;                       // strictly-higher-lane total
    if (base < nbins) {
        for (int k = per - 1; k >= 0; --k) {
            int h = hist[base + k];
            if (cum < kv && kv <= cum + h) { *s_chosen = base + k; *s_knext = kv - cum; *s_cnt = h; }
            cum += h;
        }
    }
}

// ---------------------------------------------------------------------------
// K1: full-occupancy per-(b,p) heavy work. One prior per thread; 13 chunk
// blocks per batch. Computes IoU best-truth (first-max), per-truth best-prior
// partial keys (u64 (ov_bits<<32)|~p, block-reduced, 13 partials to ws), LSE,
// and a 16 B record {bov, bidx, lse, conf[p][0]}.
// ---------------------------------------------------------------------------
__global__ __launch_bounds__(256, 6) void prep_kernel(
    const float* __restrict__ conf, const float* __restrict__ priors,
    const float* __restrict__ targets, vrec* __restrict__ recs,
    unsigned long long* __restrict__ pt)
{
    const int chunk = blockIdx.x, b = blockIdx.y;
    const int tid = threadIdx.x, lane = tid & 63, wid = tid >> 6;   // 4 waves
    const int p = chunk * 256 + tid;
    const bool valid = (p < PP);

    __shared__ float s_tx1[NOBJ], s_ty1[NOBJ], s_tx2[NOBJ], s_ty2[NOBJ], s_area[NOBJ];
    __shared__ unsigned long long s_wk[NOBJ][4];

    if (tid < NOBJ) {
        const float* t = targets + ((size_t)b * NOBJ + tid) * 5;
        float x1 = t[0], y1 = t[1], x2 = t[2], y2 = t[3];
        s_tx1[tid] = x1; s_ty1[tid] = y1; s_tx2[tid] = x2; s_ty2[tid] = y2;
        s_area[tid] = (x2 - x1) * (y2 - y1);
    }
    __syncthreads();

    // Invalid lanes use a zero prior: inter=0, area_p=0 -> iou = 0/(area_t) = 0,
    // and their reduce key is forced to 0 (loses to any real key).
    vf4 pr = {0.0f, 0.0f, 0.0f, 0.0f};
    if (valid) pr = *(const vf4*)(priors + 4 * p);
    float px1 = pr[0] - pr[2] / 2.0f, py1 = pr[1] - pr[3] / 2.0f;
    float px2 = pr[0] + pr[2] / 2.0f, py2 = pr[1] + pr[3] / 2.0f;
    float area_p = (px2 - px1) * (py2 - py1);

    float bov = -1.0f; int bidx = 0;
#pragma unroll
    for (int j = 0; j < NOBJ; ++j) {
        float ltx = fmaxf(s_tx1[j], px1);
        float lty = fmaxf(s_ty1[j], py1);
        float rbx = fminf(s_tx2[j], px2);
        float rby = fminf(s_ty2[j], py2);
        float iw = fmaxf(rbx - ltx, 0.0f);
        float ih = fmaxf(rby - lty, 0.0f);
        float inter = iw * ih;
        float iou = inter / ((s_area[j] + area_p) - inter);
        if (iou > bov) { bov = iou; bidx = j; }          // first max over truths
        // per-truth butterfly reduce, fused (no iou[12] array -> low VGPR)
        unsigned long long k = valid
            ? (((unsigned long long)__float_as_uint(iou) << 32) | (0xFFFFFFFFu - (unsigned)p))
            : 0ull;
#pragma unroll
        for (int off = 32; off > 0; off >>= 1) {
            unsigned long long k2 = __shfl_xor(k, off);
            if (k2 > k) k = k2;
        }
        if (lane == 0) s_wk[j][wid] = k;
    }

    // LSE + record (keys dead -> Row's 21 floats don't stack on reduce state).
    if (valid) {
        Row r = load_row(conf + ((size_t)b * PP + p) * NCLS);
        float lse = lse21(r);
        vrec rec;
        rec[0] = bov; rec[1] = __int_as_float(bidx); rec[2] = lse; rec[3] = r.a[0];
        recs[(size_t)b * PP + p] = rec;
    }
    __syncthreads();
    if (tid < NOBJ) {
        unsigned long long m = s_wk[tid][0];
#pragma unroll
        for (int w2 = 1; w2 < 4; ++w2) { unsigned long long v = s_wk[tid][w2]; if (v > m) m = v; }
        pt[((size_t)b * CH + chunk) * NOBJ + tid] = m;
    }
}

// ---------------------------------------------------------------------------
// K2: per-batch light work. One block/batch, 1024 threads. Streams the 16 B
// records (prefetched to registers), computes conf_t/CE/smooth-L1/keys, then
// exact radix select on 32-bit value keys (8-bit digits, 256-bin ballot-agg
// hist). Early exit without any lookup: if the crossing bin count==1, the
// selection test is (key&pmask)>=prefix (exactly one key matches ==). Rare
// value-ties resolved by two index rounds. Final single per-cell pass.
// ---------------------------------------------------------------------------
__global__ __launch_bounds__(1024, 4) void select_kernel(
    const float* __restrict__ loc, const float* __restrict__ conf,
    const float* __restrict__ priors, const float* __restrict__ targets,
    const vrec* __restrict__ recs, const unsigned long long* __restrict__ pt,
    int* __restrict__ numpos, double* __restrict__ lossl,
    double* __restrict__ lossc, float* __restrict__ out)
{
    const int b = blockIdx.x, tid = threadIdx.x;
    const int lane = tid & 63, wid = tid >> 6;   // 16 waves

    __shared__ float s_tx1[NOBJ], s_ty1[NOBJ], s_tx2[NOBJ], s_ty2[NOBJ];
    __shared__ int   s_label[NOBJ], s_bpi[NOBJ];
    __shared__ unsigned s_key[PP];
    __shared__ float s_ce[PP];
    __shared__ unsigned char s_ct[PP];
    __shared__ int s_hist[2][256];
    __shared__ int s_chosen, s_knext, s_cnt, s_nneg;
    __shared__ double s_pl[16];
    __shared__ int    s_pn[16];
    __shared__ double s_pc[16];

    // Prefetch records into registers before the first barrier.
    const vrec* rb = recs + (size_t)b * PP;
    vrec r0 = rb[tid];
    vrec r1 = rb[tid + 1024];
    vrec r2 = rb[tid + 2048];
    const bool h3 = (tid + 3072 < PP);
    vrec r3; if (h3) r3 = rb[tid + 3072];

    if (tid < NOBJ) {
        const float* t = targets + ((size_t)b * NOBJ + tid) * 5;
        s_tx1[tid] = t[0]; s_ty1[tid] = t[1]; s_tx2[tid] = t[2]; s_ty2[tid] = t[3];
        s_label[tid] = (int)t[4];
        const unsigned long long* q = pt + (size_t)b * CH * NOBJ + tid;
        unsigned long long m = q[0];
#pragma unroll
        for (int c2 = 1; c2 < CH; ++c2) {
            unsigned long long v = q[(size_t)c2 * NOBJ];
            if (v > m) m = v;
        }
        s_bpi[tid] = (int)(0xFFFFFFFFu - (unsigned)(m & 0xFFFFFFFFull));
    }
    for (int k = tid; k < 512; k += 1024) ((int*)s_hist)[k] = 0;   // clear both hists
    __syncthreads();                                               // B1

    int bpi[NOBJ];
#pragma unroll
    for (int j = 0; j < NOBJ; ++j) bpi[j] = s_bpi[j];

    int my_pos = 0;
    double my_lossl = 0.0;
    const float* confb = conf + (size_t)b * PP * NCLS;

    auto body = [&](vrec r, int p) {
        float bov = r[0]; int bidx = __float_as_int(r[1]);
        float lse = r[2]; float c0 = r[3];
        int jov = -1;
#pragma unroll
        for (int j = 0; j < NOBJ; ++j) if (bpi[j] == p) jov = j;  // last-wins on duplicates
        int idx; float ov;
        if (jov >= 0) { idx = jov; ov = 2.0f; }
        else          { idx = bidx; ov = bov; }
        int c = (ov < THRESH_) ? 0 : (s_label[idx] + 1);
        s_ct[p] = (unsigned char)c;

        float cdc = (c == 0) ? c0 : confb[(size_t)p * NCLS + c];
        float ce  = lse - cdc;
        s_ce[p] = ce;
        float v = (c > 0) ? 0.0f : ce;          // mining value (positives compete as 0)
        s_key[p] = __float_as_uint(v);          // v >= 0 -> uint order == float order

        if (c > 0) {
            ++my_pos;
            vf4 prr = *(const vf4*)(priors + 4 * p);
            float m0 = s_tx1[idx], m1 = s_ty1[idx], m2 = s_tx2[idx], m3 = s_ty2[idx];
            float g0 = ((m0 + m2) / 2.0f - prr[0]) / (0.1f * prr[2]);
            float g1 = ((m1 + m3) / 2.0f - prr[1]) / (0.1f * prr[3]);
            float g2 = logf((m2 - m0) / prr[2]) / 0.2f;
            float g3 = logf((m3 - m1) / prr[3]) / 0.2f;
            const float* ld = loc + ((size_t)b * PP + p) * 4;
            float d0 = ld[0] - g0, d1 = ld[1] - g1, d2 = ld[2] - g2, d3 = ld[3] - g3;
            float a0 = fabsf(d0), a1 = fabsf(d1), a2 = fabsf(d2), a3 = fabsf(d3);
            my_lossl += (double)((a0 < 1.0f) ? 0.5f * d0 * d0 : a0 - 0.5f);
            my_lossl += (double)((a1 < 1.0f) ? 0.5f * d1 * d1 : a1 - 0.5f);
            my_lossl += (double)((a2 < 1.0f) ? 0.5f * d2 * d2 : a2 - 0.5f);
            my_lossl += (double)((a3 < 1.0f) ? 0.5f * d3 * d3 : a3 - 0.5f);
        }
    };
    body(r0, tid); body(r1, tid + 1024); body(r2, tid + 2048);
    if (h3) body(r3, tid + 3072);

#pragma unroll
    for (int off = 32; off > 0; off >>= 1) {
        my_lossl += __shfl_down(my_lossl, off);
        my_pos   += __shfl_down(my_pos, off);
    }
    if (lane == 0) { s_pl[wid] = my_lossl; s_pn[wid] = my_pos; }
    __syncthreads();                                               // B2
    if (tid == 0) {
        double L = 0.0; int n = 0;
#pragma unroll
        for (int w2 = 0; w2 < 16; ++w2) { L += s_pl[w2]; n += s_pn[w2]; }
        lossl[b] = L; numpos[b] = n;
        s_nneg = min(3 * n, PP - 1);   // n >= 1 (forced matches)
    }

    // ---- Radix select, 8-bit digits, up to 4 rounds, early exit on cnt==1.
    unsigned prefix = 0u, pmask = 0u;
    int ptie = 0x7FFFFFFF;
    bool done = false;
    const int shifts[4] = {24, 16, 8, 0};
#pragma unroll
    for (int r = 0; r < 4; ++r) {
        if (!done) {                    // uniform branch (s_cnt same for all)
            const int sh = shifts[r];
            int* hist = s_hist[r & 1];
            for (int i = tid; i < PP; i += 1024) {
                unsigned key = s_key[i];
                agg_add<8>(hist, (key & pmask) == prefix, (key >> sh) & 0xFFu, lane);
            }
            __syncthreads();            // (round 0: also publishes s_nneg)
            if (tid < 64) pick_bin(hist, 256, (r == 0) ? s_nneg : s_knext, lane,
                                   &s_chosen, &s_knext, &s_cnt);
            else { for (int k = tid - 64; k < 256; k += 960) s_hist[(r + 1) & 1][k] = 0; }
            __syncthreads();
            prefix |= ((unsigned)s_chosen) << sh;
            pmask  |= 0xFFu << sh;
            if (s_cnt == 1) done = true;
        }
    }

    // Rare: kk-th lies inside a tied-value group -> resolve index threshold
    // (smallest-p-first among equal values, matching the stable argsort).
    if (!done && s_knext < s_cnt) {
        int* hist = s_hist[0];          // cleared during round 3's pick
        for (int i = tid; i < PP; i += 1024)
            agg_add<8>(hist, s_key[i] == prefix, ((4095u - (unsigned)i) >> 4) & 0xFFu, lane);
        __syncthreads();
        if (tid < 64) pick_bin(hist, 256, s_knext, lane, &s_chosen, &s_knext, &s_cnt);
        else { for (int k = tid - 64; k < 256; k += 960) s_hist[1][k] = 0; }
        __syncthreads();
        const int binA = s_chosen;
        int* hist2 = s_hist[1];
        for (int i = tid; i < PP; i += 1024) {
            unsigned hi = 4095u - (unsigned)i;
            agg_add<4>(hist2, (s_key[i] == prefix) && (((hi >> 4) & 0xFFu) == (unsigned)binA),
                       hi & 0xFu, lane);
        }
        __syncthreads();
        if (tid < 64) pick_bin(hist2, 16, s_knext, lane, &s_chosen, &s_knext, &s_cnt);
        __syncthreads();
        ptie = 4095 - ((binA << 4) | s_chosen);
    }

    // ---- Final per-cell pass: selection, loss_c, featuremap outputs.
    // sel_neg = masked-key > prefix, or == prefix and p <= ptie. With the
    // cnt==1 early exit exactly one key matches ==, ptie=+inf selects it.
    double my_c = 0.0;
    for (int cI = tid; cI < CELLS; cI += 1024) {
        int mc = 0, hv = 0;
#pragma unroll
        for (int a = 0; a < 9; ++a) {
            int p = cI * 9 + a;
            int cv = s_ct[p];
            unsigned km = s_key[p] & pmask;
            bool sel = (cv > 0) || (km > prefix) || (km == prefix && p <= ptie);
            mc = (cv > mc) ? cv : mc;
            hv |= sel ? 1 : 0;
            if (sel) my_c += (double)s_ce[p];
        }
        out[2 + (size_t)b * CELLS + cI] = (float)mc;
        out[2 + (size_t)BB * CELLS + (size_t)b * CELLS + cI] = (float)hv;
    }

#pragma unroll
    for (int off = 32; off > 0; off >>= 1) my_c += __shfl_down(my_c, off);
    if (lane == 0) s_pc[wid] = my_c;
    __syncthreads();
    if (tid == 0) {
        double L = 0.0;
#pragma unroll
        for (int w2 = 0; w2 < 16; ++w2) L += s_pc[w2];
        lossc[b] = L;
    }
}

__global__ __launch_bounds__(256) void finalize_kernel(
    const int* __restrict__ numpos, const double* __restrict__ lossl,
    const double* __restrict__ lossc, float* __restrict__ out)
{
    __shared__ double s_l[256], s_c[256];
    __shared__ int s_n[256];
    int tid = threadIdx.x;
    s_n[tid] = numpos[tid];     // BB == 256 == blockDim
    s_l[tid] = lossl[tid];
    s_c[tid] = lossc[tid];
    __syncthreads();
    for (int s = 128; s > 0; s >>= 1) {
        if (tid < s) { s_n[tid] += s_n[tid + s]; s_l[tid] += s_l[tid + s]; s_c[tid] += s_c[tid + s]; }
        __syncthreads();
    }
    if (tid == 0) {
        double N = (double)s_n[0];
        out[0] = (float)(s_l[0] / N);
        out[1] = (float)(s_c[0] / N);
    }
}

extern "C" void kernel_launch(void* const* d_in, const int* in_sizes, int n_in,
                              void* d_out, int out_size, void* d_ws, size_t ws_size,
                              hipStream_t stream) {
    const float* loc     = (const float*)d_in[0];  // (B, P, 4)
    const float* conf    = (const float*)d_in[1];  // (B, P, 21)
    const float* priors  = (const float*)d_in[2];  // (P, 4)
    const float* targets = (const float*)d_in[3];  // (B, 12, 5)
    float* out = (float*)d_out;

    double* ws_lossl  = (double*)d_ws;                       // 256 doubles
    double* ws_lossc  = ws_lossl + BB;                       // 256 doubles
    int*    ws_numpos = (int*)(ws_lossc + BB);               // 256 ints
    unsigned long long* ws_pt = (unsigned long long*)(ws_numpos + BB);   // 256*13*12 u64
    vrec*   ws_rec    = (vrec*)(ws_pt + (size_t)BB * CH * NOBJ);         // 256*3249 x 16 B

    hipLaunchKernelGGL(prep_kernel, dim3(CH, BB), dim3(256), 0, stream,
                       conf, priors, targets, ws_rec, ws_pt);
    hipLaunchKernelGGL(select_kernel, dim3(BB), dim3(1024), 0, stream,
                       loc, conf, priors, targets, ws_rec, ws_pt,
                       ws_numpos, ws_lossl, ws_lossc, out);
    hipLaunchKernelGGL(finalize_kernel, dim3(1), dim3(256), 0, stream,
                       ws_numpos, ws_lossl, ws_lossc, out);
}

// Round 4
// 141.925 us; speedup vs baseline: 1.0053x; 1.0053x over previous
//
#include <hip/hip_runtime.h>
#include <math.h>

// Match numpy reference numerics exactly: no FMA contraction anywhere.
// Matching decisions (argmax ties, ov<0.5 threshold) rest on bit-exact floats.
#pragma clang fp contract(off)

#define BB      256
#define PP      3249         // 19*19*9
#define NCLS    21
#define NOBJ    12
#define CELLS   361          // 19*19
#define CH      13           // prior chunks of 256 per batch (13*256 >= 3249)
#define THRESH_ 0.5f

// 4-float vector with 4-byte alignment: conf rows (84 B) are only dword-aligned.
typedef float vf4 __attribute__((ext_vector_type(4), aligned(4)));
// 16-byte-aligned record vector.
typedef float vrec __attribute__((ext_vector_type(4)));

// d_out layout (float32): [0]=loss_l/N, [1]=loss_c/N,
// [2 .. 2+BB*CELLS) = conf_t_featuremap, [2+BB*CELLS .. 2+2*BB*CELLS) = have_centerloss

struct Row { vf4 a, b, c, d, e; float f; };

__device__ __forceinline__ Row load_row(const float* cd) {
    const vf4* q = (const vf4*)cd;
    Row r;
    r.a = q[0]; r.b = q[1]; r.c = q[2]; r.d = q[3]; r.e = q[4];
    r.f = cd[20];
    return r;
}

// lse identical to reference op order: m = max chain k=0..20; s = sum of
// expf(x-m) k=0..20; result logf(s)+m (rounded float -> later ce = lse-conf[c]
// is bit-identical to computing ce inline).
__device__ __forceinline__ float lse21(const Row& r) {
    float m = r.a[0];
    m = fmaxf(m, r.a[1]); m = fmaxf(m, r.a[2]); m = fmaxf(m, r.a[3]);
    m = fmaxf(m, r.b[0]); m = fmaxf(m, r.b[1]); m = fmaxf(m, r.b[2]); m = fmaxf(m, r.b[3]);
    m = fmaxf(m, r.c[0]); m = fmaxf(m, r.c[1]); m = fmaxf(m, r.c[2]); m = fmaxf(m, r.c[3]);
    m = fmaxf(m, r.d[0]); m = fmaxf(m, r.d[1]); m = fmaxf(m, r.d[2]); m = fmaxf(m, r.d[3]);
    m = fmaxf(m, r.e[0]); m = fmaxf(m, r.e[1]); m = fmaxf(m, r.e[2]); m = fmaxf(m, r.e[3]);
    m = fmaxf(m, r.f);
    float s = 0.0f;
    s += expf(r.a[0]-m); s += expf(r.a[1]-m); s += expf(r.a[2]-m); s += expf(r.a[3]-m);
    s += expf(r.b[0]-m); s += expf(r.b[1]-m); s += expf(r.b[2]-m); s += expf(r.b[3]-m);
    s += expf(r.c[0]-m); s += expf(r.c[1]-m); s += expf(r.c[2]-m); s += expf(r.c[3]-m);
    s += expf(r.d[0]-m); s += expf(r.d[1]-m); s += expf(r.d[2]-m); s += expf(r.d[3]-m);
    s += expf(r.e[0]-m); s += expf(r.e[1]-m); s += expf(r.e[2]-m); s += expf(r.e[3]-m);
    s += expf(r.f-m);
    return logf(s) + m;
}

// Ballot-aggregated histogram add: equal-bin lane groups found with NBITS
// ballots; lowest lane of each group does ONE atomicAdd of popcount. Lanes
// not executing (loop tail) are simply absent from the exec-mask ballots.
template <int NBITS>
__device__ __forceinline__ void agg_add(int* hist, bool active, unsigned bin, int lane) {
    unsigned long long mm = __ballot(active);
#pragma unroll
    for (int bit = 0; bit < NBITS; ++bit) {
        unsigned long long bb = __ballot(active && ((bin >> bit) & 1));
        mm &= ((bin >> bit) & 1) ? bb : ~bb;
    }
    if (active && (__ffsll(mm) - 1 == lane))
        atomicAdd(&hist[bin], (int)__popcll(mm));
}

// Wave-0 pick: find the bin where the top-down (descending-bin) cumulative
// count crosses kv. Lane l owns bins [l*per,(l+1)*per) (per>=1); butterfly
// suffix-sum over lanes, then high->low walk within the lane. nbins may be <64.
__device__ __forceinline__ void pick_bin(const int* hist, int nbins, int kv, int lane,
                                         int* s_chosen, int* s_knext, int* s_cnt) {
    const int per = (nbins >= 64) ? (nbins >> 6) : 1;
    const int base = lane * per;
    int ls = 0;
    if (base < nbins)
        for (int k = 0; k < per; ++k) ls += hist[base + k];
    int x = ls;
#pragma unroll
    for (int off = 1; off < 64; off <<= 1) {
        int y = __shfl_down(x, off);
        if (lane + off < 64) x += y;
    }
    int cum = x - ls;                       // strictly-higher-lane total
    if (base < nbins) {
        for (int k = per - 1; k >= 0; --k) {
            int h = hist[base + k];
            if (cum < kv && kv <= cum + h) { *s_chosen = base + k; *s_knext = kv - cum; *s_cnt = h; }
            cum += h;
        }
    }
}

// ---------------------------------------------------------------------------
// K1: full-occupancy per-(b,p) heavy work. One prior per thread; 13 chunk
// blocks per batch. Conf row issued BEFORE the IoU work so its ~900cy HBM
// latency hides under compute. Per-truth reduce: f32 max butterfly + one
// ballot; the lowest tying lane is the smallest p (== reference first-max).
// Also zeroes the select-completion counter (ws is harness-poisoned).
// ---------------------------------------------------------------------------
__global__ __launch_bounds__(256, 4) void prep_kernel(
    const float* __restrict__ conf, const float* __restrict__ priors,
    const float* __restrict__ targets, vrec* __restrict__ recs,
    unsigned long long* __restrict__ pt, int* __restrict__ done)
{
    const int chunk = blockIdx.x, b = blockIdx.y;
    const int tid = threadIdx.x, lane = tid & 63, wid = tid >> 6;   // 4 waves
    const int p = chunk * 256 + tid;
    const bool valid = (p < PP);

    if (chunk == 0 && b == 0 && tid == 0) *done = 0;   // reset before select runs

    __shared__ float s_tx1[NOBJ], s_ty1[NOBJ], s_tx2[NOBJ], s_ty2[NOBJ], s_area[NOBJ];
    __shared__ unsigned long long s_wk[NOBJ][4];

    // Issue long-latency loads first (neither depends on targets/LDS).
    vf4 pr = {0.0f, 0.0f, 0.0f, 0.0f};
    if (valid) pr = *(const vf4*)(priors + 4 * p);
    Row r = load_row(conf + ((size_t)b * PP + (valid ? p : 0)) * NCLS);

    if (tid < NOBJ) {
        const float* t = targets + ((size_t)b * NOBJ + tid) * 5;
        float x1 = t[0], y1 = t[1], x2 = t[2], y2 = t[3];
        s_tx1[tid] = x1; s_ty1[tid] = y1; s_tx2[tid] = x2; s_ty2[tid] = y2;
        s_area[tid] = (x2 - x1) * (y2 - y1);
    }
    __syncthreads();

    // Invalid lanes use a zero prior: inter=0, area_p=0 -> iou = 0/area_t = 0.
    // They sit at high lane indices, so a ballot tie at 0 still resolves to a
    // valid (smaller-p) lane; an all-invalid wave's key always loses to any
    // valid wave's key (equal ov word -> larger p -> smaller ~p word).
    float px1 = pr[0] - pr[2] / 2.0f, py1 = pr[1] - pr[3] / 2.0f;
    float px2 = pr[0] + pr[2] / 2.0f, py2 = pr[1] + pr[3] / 2.0f;
    float area_p = (px2 - px1) * (py2 - py1);

    float bov = -1.0f; int bidx = 0;
#pragma unroll
    for (int j = 0; j < NOBJ; ++j) {
        float ltx = fmaxf(s_tx1[j], px1);
        float lty = fmaxf(s_ty1[j], py1);
        float rbx = fminf(s_tx2[j], px2);
        float rby = fminf(s_ty2[j], py2);
        float iw = fmaxf(rbx - ltx, 0.0f);
        float ih = fmaxf(rby - lty, 0.0f);
        float inter = iw * ih;
        float iou = inter / ((s_area[j] + area_p) - inter);
        if (iou > bov) { bov = iou; bidx = j; }          // first max over truths
        // Per-truth wave reduce: f32 butterfly max, then one ballot picks the
        // lowest tying lane == smallest p (reference argmax tie rule).
        float m = iou;
#pragma unroll
        for (int off = 32; off > 0; off >>= 1)
            m = fmaxf(m, __shfl_xor(m, off));
        unsigned long long win = __ballot(iou == m);
        if (lane == 0) {
            int pw = chunk * 256 + wid * 64 + (__ffsll(win) - 1);
            s_wk[j][wid] = ((unsigned long long)__float_as_uint(m) << 32)
                         | (0xFFFFFFFFu - (unsigned)pw);
        }
    }

    // LSE + record (reduce keys dead -> Row doesn't stack on reduce state).
    if (valid) {
        float lse = lse21(r);
        vrec rec;
        rec[0] = bov; rec[1] = __int_as_float(bidx); rec[2] = lse; rec[3] = r.a[0];
        recs[(size_t)b * PP + p] = rec;
    }
    __syncthreads();
    if (tid < NOBJ) {
        unsigned long long m = s_wk[tid][0];
#pragma unroll
        for (int w2 = 1; w2 < 4; ++w2) { unsigned long long v = s_wk[tid][w2]; if (v > m) m = v; }
        pt[((size_t)b * CH + chunk) * NOBJ + tid] = m;
    }
}

// ---------------------------------------------------------------------------
// K2: per-batch light work. One block/batch, 1024 threads. Streams the 16 B
// records (prefetched to registers), computes conf_t/CE/smooth-L1/keys, then
// exact radix select on 32-bit value keys (8-bit digits, 256-bin ballot-agg
// hist). Early exit without any lookup: if the crossing bin count==1, the
// selection test is (key&pmask)>=prefix. Rare value-ties resolved by two
// index rounds. Final per-cell pass, then last-block-done global finalize
// (replaces the third kernel launch).
// ---------------------------------------------------------------------------
__global__ __launch_bounds__(1024, 4) void select_kernel(
    const float* __restrict__ loc, const float* __restrict__ conf,
    const float* __restrict__ priors, const float* __restrict__ targets,
    const vrec* __restrict__ recs, const unsigned long long* __restrict__ pt,
    int* __restrict__ numpos, double* __restrict__ lossl,
    double* __restrict__ lossc, int* __restrict__ done, float* __restrict__ out)
{
    const int b = blockIdx.x, tid = threadIdx.x;
    const int lane = tid & 63, wid = tid >> 6;   // 16 waves

    __shared__ float s_tx1[NOBJ], s_ty1[NOBJ], s_tx2[NOBJ], s_ty2[NOBJ];
    __shared__ int   s_label[NOBJ], s_bpi[NOBJ];
    __shared__ unsigned s_key[PP];
    __shared__ float s_ce[PP];
    __shared__ unsigned char s_ct[PP];
    __shared__ int s_hist[2][256];
    __shared__ int s_chosen, s_knext, s_cnt, s_nneg, s_last;
    __shared__ double s_pl[16];
    __shared__ int    s_pn[16];
    __shared__ double s_pc[16];
    __shared__ double s_fl[4], s_fc[4];
    __shared__ int    s_fn[4];

    // Prefetch records into registers before the first barrier.
    const vrec* rb = recs + (size_t)b * PP;
    vrec r0 = rb[tid];
    vrec r1 = rb[tid + 1024];
    vrec r2 = rb[tid + 2048];
    const bool h3 = (tid + 3072 < PP);
    vrec r3; if (h3) r3 = rb[tid + 3072];

    if (tid < NOBJ) {
        const float* t = targets + ((size_t)b * NOBJ + tid) * 5;
        s_tx1[tid] = t[0]; s_ty1[tid] = t[1]; s_tx2[tid] = t[2]; s_ty2[tid] = t[3];
        s_label[tid] = (int)t[4];
        const unsigned long long* q = pt + (size_t)b * CH * NOBJ + tid;
        unsigned long long m = q[0];
#pragma unroll
        for (int c2 = 1; c2 < CH; ++c2) {
            unsigned long long v = q[(size_t)c2 * NOBJ];
            if (v > m) m = v;
        }
        s_bpi[tid] = (int)(0xFFFFFFFFu - (unsigned)(m & 0xFFFFFFFFull));
    }
    for (int k = tid; k < 512; k += 1024) ((int*)s_hist)[k] = 0;   // clear both hists
    __syncthreads();                                               // B1

    int bpi[NOBJ];
#pragma unroll
    for (int j = 0; j < NOBJ; ++j) bpi[j] = s_bpi[j];

    int my_pos = 0;
    double my_lossl = 0.0;
    const float* confb = conf + (size_t)b * PP * NCLS;

    auto body = [&](vrec r, int p) {
        float bov = r[0]; int bidx = __float_as_int(r[1]);
        float lse = r[2]; float c0 = r[3];
        int jov = -1;
#pragma unroll
        for (int j = 0; j < NOBJ; ++j) if (bpi[j] == p) jov = j;  // last-wins on duplicates
        int idx; float ov;
        if (jov >= 0) { idx = jov; ov = 2.0f; }
        else          { idx = bidx; ov = bov; }
        int c = (ov < THRESH_) ? 0 : (s_label[idx] + 1);
        s_ct[p] = (unsigned char)c;

        float cdc = (c == 0) ? c0 : confb[(size_t)p * NCLS + c];
        float ce  = lse - cdc;
        s_ce[p] = ce;
        float v = (c > 0) ? 0.0f : ce;          // mining value (positives compete as 0)
        s_key[p] = __float_as_uint(v);          // v >= 0 -> uint order == float order

        if (c > 0) {
            ++my_pos;
            vf4 prr = *(const vf4*)(priors + 4 * p);
            float m0 = s_tx1[idx], m1 = s_ty1[idx], m2 = s_tx2[idx], m3 = s_ty2[idx];
            float g0 = ((m0 + m2) / 2.0f - prr[0]) / (0.1f * prr[2]);
            float g1 = ((m1 + m3) / 2.0f - prr[1]) / (0.1f * prr[3]);
            float g2 = logf((m2 - m0) / prr[2]) / 0.2f;
            float g3 = logf((m3 - m1) / prr[3]) / 0.2f;
            const float* ld = loc + ((size_t)b * PP + p) * 4;
            float d0 = ld[0] - g0, d1 = ld[1] - g1, d2 = ld[2] - g2, d3 = ld[3] - g3;
            float a0 = fabsf(d0), a1 = fabsf(d1), a2 = fabsf(d2), a3 = fabsf(d3);
            my_lossl += (double)((a0 < 1.0f) ? 0.5f * d0 * d0 : a0 - 0.5f);
            my_lossl += (double)((a1 < 1.0f) ? 0.5f * d1 * d1 : a1 - 0.5f);
            my_lossl += (double)((a2 < 1.0f) ? 0.5f * d2 * d2 : a2 - 0.5f);
            my_lossl += (double)((a3 < 1.0f) ? 0.5f * d3 * d3 : a3 - 0.5f);
        }
    };
    body(r0, tid); body(r1, tid + 1024); body(r2, tid + 2048);
    if (h3) body(r3, tid + 3072);

#pragma unroll
    for (int off = 32; off > 0; off >>= 1) {
        my_lossl += __shfl_down(my_lossl, off);
        my_pos   += __shfl_down(my_pos, off);
    }
    if (lane == 0) { s_pl[wid] = my_lossl; s_pn[wid] = my_pos; }
    __syncthreads();                                               // B2
    if (tid == 0) {
        double L = 0.0; int n = 0;
#pragma unroll
        for (int w2 = 0; w2 < 16; ++w2) { L += s_pl[w2]; n += s_pn[w2]; }
        lossl[b] = L; numpos[b] = n;
        s_nneg = min(3 * n, PP - 1);   // n >= 1 (forced matches)
    }

    // ---- Radix select, 8-bit digits, up to 4 rounds, early exit on cnt==1.
    unsigned prefix = 0u, pmask = 0u;
    int ptie = 0x7FFFFFFF;
    bool done_sel = false;
    const int shifts[4] = {24, 16, 8, 0};
#pragma unroll
    for (int r = 0; r < 4; ++r) {
        if (!done_sel) {                // uniform branch (s_cnt same for all)
            const int sh = shifts[r];
            int* hist = s_hist[r & 1];
            for (int i = tid; i < PP; i += 1024) {
                unsigned key = s_key[i];
                agg_add<8>(hist, (key & pmask) == prefix, (key >> sh) & 0xFFu, lane);
            }
            __syncthreads();            // (round 0: also publishes s_nneg)
            if (tid < 64) pick_bin(hist, 256, (r == 0) ? s_nneg : s_knext, lane,
                                   &s_chosen, &s_knext, &s_cnt);
            else { for (int k = tid - 64; k < 256; k += 960) s_hist[(r + 1) & 1][k] = 0; }
            __syncthreads();
            prefix |= ((unsigned)s_chosen) << sh;
            pmask  |= 0xFFu << sh;
            if (s_cnt == 1) done_sel = true;
        }
    }

    // Rare: kk-th lies inside a tied-value group -> resolve index threshold
    // (smallest-p-first among equal values, matching the stable argsort).
    if (!done_sel && s_knext < s_cnt) {
        int* hist = s_hist[0];          // cleared during round 3's pick
        for (int i = tid; i < PP; i += 1024)
            agg_add<8>(hist, s_key[i] == prefix, ((4095u - (unsigned)i) >> 4) & 0xFFu, lane);
        __syncthreads();
        if (tid < 64) pick_bin(hist, 256, s_knext, lane, &s_chosen, &s_knext, &s_cnt);
        else { for (int k = tid - 64; k < 256; k += 960) s_hist[1][k] = 0; }
        __syncthreads();
        const int binA = s_chosen;
        int* hist2 = s_hist[1];
        for (int i = tid; i < PP; i += 1024) {
            unsigned hi = 4095u - (unsigned)i;
            agg_add<4>(hist2, (s_key[i] == prefix) && (((hi >> 4) & 0xFFu) == (unsigned)binA),
                       hi & 0xFu, lane);
        }
        __syncthreads();
        if (tid < 64) pick_bin(hist2, 16, s_knext, lane, &s_chosen, &s_knext, &s_cnt);
        __syncthreads();
        ptie = 4095 - ((binA << 4) | s_chosen);
    }

    // ---- Final per-cell pass: selection, loss_c, featuremap outputs.
    // sel_neg = masked-key > prefix, or == prefix and p <= ptie. With the
    // cnt==1 early exit exactly one key matches ==, ptie=+inf selects it.
    double my_c = 0.0;
    for (int cI = tid; cI < CELLS; cI += 1024) {
        int mc = 0, hv = 0;
#pragma unroll
        for (int a = 0; a < 9; ++a) {
            int p = cI * 9 + a;
            int cv = s_ct[p];
            unsigned km = s_key[p] & pmask;
            bool sel = (cv > 0) || (km > prefix) || (km == prefix && p <= ptie);
            mc = (cv > mc) ? cv : mc;
            hv |= sel ? 1 : 0;
            if (sel) my_c += (double)s_ce[p];
        }
        out[2 + (size_t)b * CELLS + cI] = (float)mc;
        out[2 + (size_t)BB * CELLS + (size_t)b * CELLS + cI] = (float)hv;
    }

#pragma unroll
    for (int off = 32; off > 0; off >>= 1) my_c += __shfl_down(my_c, off);
    if (lane == 0) s_pc[wid] = my_c;
    __syncthreads();
    if (tid == 0) {
        double L = 0.0;
#pragma unroll
        for (int w2 = 0; w2 < 16; ++w2) L += s_pc[w2];
        lossc[b] = L;
        // Publish this batch's results, then bump the completion counter.
        __threadfence();
        int prev = atomicAdd(done, 1);
        s_last = (prev == BB - 1) ? 1 : 0;
    }
    __syncthreads();

    // Last block standing folds the 256 per-batch partials (replaces kernel 3).
    if (s_last) {
        double fl = 0.0, fc = 0.0; int fn = 0;
        if (tid < BB) { fl = lossl[tid]; fc = lossc[tid]; fn = numpos[tid]; }
        if (tid < BB) {
#pragma unroll
            for (int off = 32; off > 0; off >>= 1) {
                fl += __shfl_down(fl, off);
                fc += __shfl_down(fc, off);
                fn += __shfl_down(fn, off);
            }
            if (lane == 0) { s_fl[wid] = fl; s_fc[wid] = fc; s_fn[wid] = fn; }
        }
        __syncthreads();
        if (tid == 0) {
            double L = s_fl[0] + s_fl[1] + s_fl[2] + s_fl[3];
            double C = s_fc[0] + s_fc[1] + s_fc[2] + s_fc[3];
            double N = (double)(s_fn[0] + s_fn[1] + s_fn[2] + s_fn[3]);
            out[0] = (float)(L / N);
            out[1] = (float)(C / N);
        }
    }
}

extern "C" void kernel_launch(void* const* d_in, const int* in_sizes, int n_in,
                              void* d_out, int out_size, void* d_ws, size_t ws_size,
                              hipStream_t stream) {
    const float* loc     = (const float*)d_in[0];  // (B, P, 4)
    const float* conf    = (const float*)d_in[1];  // (B, P, 21)
    const float* priors  = (const float*)d_in[2];  // (P, 4)
    const float* targets = (const float*)d_in[3];  // (B, 12, 5)
    float* out = (float*)d_out;

    // ws layout (16B-aligned tail for records):
    double* ws_lossl  = (double*)d_ws;                       // [0, 2048)
    double* ws_lossc  = ws_lossl + BB;                       // [2048, 4096)
    int*    ws_numpos = (int*)(ws_lossc + BB);               // [4096, 5120)
    int*    ws_done   = ws_numpos + BB;                      // [5120, 5136) (4 ints)
    unsigned long long* ws_pt = (unsigned long long*)(ws_done + 4);      // [5136, +319488)
    vrec*   ws_rec    = (vrec*)(ws_pt + (size_t)BB * CH * NOBJ);         // 16B-aligned

    hipLaunchKernelGGL(prep_kernel, dim3(CH, BB), dim3(256), 0, stream,
                       conf, priors, targets, ws_rec, ws_pt, ws_done);
    hipLaunchKernelGGL(select_kernel, dim3(BB), dim3(1024), 0, stream,
                       loc, conf, priors, targets, ws_rec, ws_pt,
                       ws_numpos, ws_lossl, ws_lossc, ws_done, out);
}